// Round 1
// baseline (280.108 us; speedup 1.0000x reference)
//
#include <hip/hip_runtime.h>
#include <stdint.h>

typedef unsigned short u16;
typedef __bf16 bf16x8 __attribute__((ext_vector_type(8)));
typedef float f32x4 __attribute__((ext_vector_type(4)));

#define MM 2
#define NN 8
#define CC 1024
#define DD 256
#define BB 32
#define SS 512

__device__ __forceinline__ u16 f2bf(float f) {
  uint32_t u = __float_as_uint(f);
  u += 0x7FFFu + ((u >> 16) & 1u);   // round-to-nearest-even
  return (u16)(u >> 16);
}

__device__ __forceinline__ void async16(const void* g, void* l) {
  __builtin_amdgcn_global_load_lds(
      (const __attribute__((address_space(1))) uint32_t*)g,
      (__attribute__((address_space(3))) uint32_t*)l, 16, 0, 0);
}

// ---------------- fp32 -> bf16 elementwise (x) ----------------
__global__ __launch_bounds__(256) void cvt_f32_bf16(
    const float* __restrict__ in, u16* __restrict__ out, int n) {
  int i = (blockIdx.x * 256 + threadIdx.x) * 4;
  if (i >= n) return;
  float4 v = *reinterpret_cast<const float4*>(in + i);
  u16 o[4] = {f2bf(v.x), f2bf(v.y), f2bf(v.z), f2bf(v.w)};
  *reinterpret_cast<uint2*>(out + i) = *reinterpret_cast<const uint2*>(o);
}

// ---------------- fp32 (R,L) -> bf16 (L,R) transpose per slab ----------------
// grid: (L/32, R/32, slabs), block 256
__global__ __launch_bounds__(256) void transpose_cvt(
    const float* __restrict__ in, u16* __restrict__ out, int R, int L) {
  __shared__ float tile[32][33];
  const int slab = blockIdx.z;
  const float* src = in + (size_t)slab * R * L;
  u16* dst = out + (size_t)slab * R * L;
  const int c0 = blockIdx.x * 32;  // col base (L dim)
  const int r0 = blockIdx.y * 32;  // row base (R dim)
  const int tx = threadIdx.x & 31, ty = threadIdx.x >> 5;  // 32x8
#pragma unroll
  for (int i = 0; i < 32; i += 8)
    tile[ty + i][tx] = src[(size_t)(r0 + ty + i) * L + c0 + tx];
  __syncthreads();
#pragma unroll
  for (int i = 0; i < 32; i += 8)
    dst[(size_t)(c0 + ty + i) * R + r0 + tx] = f2bf(tile[tx][ty + i]);
}

// ---------------- GEMM1: z = silu(x @ Wd + b) ----------------
// A: xb[b][S][C] bf16 (k=C contiguous). B: wdT[(m*N+e)][D][C] bf16 (k contiguous).
// out: z[pair][S][D] bf16. grid (D/128=2, S/128=4, M*B=64), 256 thr.
__global__ __launch_bounds__(256) void gemm_down(
    const u16* __restrict__ xb, const u16* __restrict__ wdT,
    const float* __restrict__ db, const int* __restrict__ eidx,
    u16* __restrict__ z) {
  __shared__ __align__(16) u16 smA[128 * 32];
  __shared__ __align__(16) u16 smB[128 * 32];

  const int pair = blockIdx.z;
  const int m = pair >> 5;   // / BB
  const int b = pair & 31;
  const int e = eidx[pair];
  const int s0 = blockIdx.y * 128;
  const int d0 = blockIdx.x * 128;

  const int tid = threadIdx.x;
  const int lane = tid & 63;
  const int wave = tid >> 6;
  const int quad = lane >> 4;
  const int l16 = lane & 15;

  const u16* Ab = xb + ((size_t)b * SS + s0) * CC;
  const u16* Bb = wdT + ((size_t)(m * NN + e) * DD + d0) * CC;

  // staging: inst t of wave w covers rows (w*2+t)*16 + lane/4, 16B chunk lane%4
  const int r0r = (wave * 2 + 0) * 16 + (lane >> 2);
  const int r1r = (wave * 2 + 1) * 16 + (lane >> 2);
  const int kc = (lane & 3) * 8;
  const u16* gA0 = Ab + (size_t)r0r * CC + kc;
  const u16* gA1 = Ab + (size_t)r1r * CC + kc;
  const u16* gB0 = Bb + (size_t)r0r * CC + kc;
  const u16* gB1 = Bb + (size_t)r1r * CC + kc;
  u16* lA0 = smA + (wave * 2 + 0) * 512;
  u16* lA1 = smA + (wave * 2 + 1) * 512;
  u16* lB0 = smB + (wave * 2 + 0) * 512;
  u16* lB1 = smB + (wave * 2 + 1) * 512;

  const int wr = (wave >> 1) * 64;
  const int wc = (wave & 1) * 64;

  f32x4 acc[4][4];
#pragma unroll
  for (int i = 0; i < 4; ++i)
#pragma unroll
    for (int j = 0; j < 4; ++j) acc[i][j] = (f32x4){0.f, 0.f, 0.f, 0.f};

  for (int kk = 0; kk < CC; kk += 32) {
    async16(gA0 + kk, lA0);
    async16(gA1 + kk, lA1);
    async16(gB0 + kk, lB0);
    async16(gB1 + kk, lB1);
    __syncthreads();
    bf16x8 af[4], bfr[4];
#pragma unroll
    for (int i = 0; i < 4; ++i)
      af[i] = *reinterpret_cast<const bf16x8*>(&smA[(wr + i * 16 + l16) * 32 + quad * 8]);
#pragma unroll
    for (int j = 0; j < 4; ++j)
      bfr[j] = *reinterpret_cast<const bf16x8*>(&smB[(wc + j * 16 + l16) * 32 + quad * 8]);
#pragma unroll
    for (int i = 0; i < 4; ++i)
#pragma unroll
      for (int j = 0; j < 4; ++j)
        acc[i][j] = __builtin_amdgcn_mfma_f32_16x16x32_bf16(af[i], bfr[j], acc[i][j], 0, 0, 0);
    __syncthreads();
  }

  const float* bias_p = db + (size_t)(m * NN + e) * DD + d0;
  u16* zb = z + (size_t)pair * SS * DD;
#pragma unroll
  for (int j = 0; j < 4; ++j) {
    const int dloc = wc + j * 16 + l16;
    const float bias = bias_p[dloc];
#pragma unroll
    for (int i = 0; i < 4; ++i) {
      const int srow = s0 + wr + i * 16 + quad * 4;
#pragma unroll
      for (int r = 0; r < 4; ++r) {
        float v = acc[i][j][r] + bias;
        v = v / (1.f + __expf(-v));  // silu
        zb[(size_t)(srow + r) * DD + d0 + dloc] = f2bf(v);
      }
    }
  }
}

// ---------------- GEMM2: u = z @ Wu ----------------
// A: z[pair][S][D] bf16 (k=D contiguous). B: wuT[(m*N+e)][C][D] bf16 (k contiguous).
// out: u[pair][S][C] fp32. grid (C/128=8, S/128=4, 64), 256 thr.
__global__ __launch_bounds__(256) void gemm_up(
    const u16* __restrict__ zb, const u16* __restrict__ wuT,
    const int* __restrict__ eidx, float* __restrict__ out) {
  __shared__ __align__(16) u16 smA[128 * 32];
  __shared__ __align__(16) u16 smB[128 * 32];

  const int pair = blockIdx.z;
  const int m = pair >> 5;
  const int e = eidx[pair];
  const int s0 = blockIdx.y * 128;
  const int c0 = blockIdx.x * 128;

  const int tid = threadIdx.x;
  const int lane = tid & 63;
  const int wave = tid >> 6;
  const int quad = lane >> 4;
  const int l16 = lane & 15;

  const u16* Ab = zb + ((size_t)pair * SS + s0) * DD;
  const u16* Bb = wuT + ((size_t)(m * NN + e) * CC + c0) * DD;

  const int r0r = (wave * 2 + 0) * 16 + (lane >> 2);
  const int r1r = (wave * 2 + 1) * 16 + (lane >> 2);
  const int kc = (lane & 3) * 8;
  const u16* gA0 = Ab + (size_t)r0r * DD + kc;
  const u16* gA1 = Ab + (size_t)r1r * DD + kc;
  const u16* gB0 = Bb + (size_t)r0r * DD + kc;
  const u16* gB1 = Bb + (size_t)r1r * DD + kc;
  u16* lA0 = smA + (wave * 2 + 0) * 512;
  u16* lA1 = smA + (wave * 2 + 1) * 512;
  u16* lB0 = smB + (wave * 2 + 0) * 512;
  u16* lB1 = smB + (wave * 2 + 1) * 512;

  const int wr = (wave >> 1) * 64;
  const int wc = (wave & 1) * 64;

  f32x4 acc[4][4];
#pragma unroll
  for (int i = 0; i < 4; ++i)
#pragma unroll
    for (int j = 0; j < 4; ++j) acc[i][j] = (f32x4){0.f, 0.f, 0.f, 0.f};

  for (int kk = 0; kk < DD; kk += 32) {
    async16(gA0 + kk, lA0);
    async16(gA1 + kk, lA1);
    async16(gB0 + kk, lB0);
    async16(gB1 + kk, lB1);
    __syncthreads();
    bf16x8 af[4], bfr[4];
#pragma unroll
    for (int i = 0; i < 4; ++i)
      af[i] = *reinterpret_cast<const bf16x8*>(&smA[(wr + i * 16 + l16) * 32 + quad * 8]);
#pragma unroll
    for (int j = 0; j < 4; ++j)
      bfr[j] = *reinterpret_cast<const bf16x8*>(&smB[(wc + j * 16 + l16) * 32 + quad * 8]);
#pragma unroll
    for (int i = 0; i < 4; ++i)
#pragma unroll
      for (int j = 0; j < 4; ++j)
        acc[i][j] = __builtin_amdgcn_mfma_f32_16x16x32_bf16(af[i], bfr[j], acc[i][j], 0, 0, 0);
    __syncthreads();
  }

  float* ob = out + (size_t)pair * SS * CC;
#pragma unroll
  for (int j = 0; j < 4; ++j) {
    const int cloc = c0 + wc + j * 16 + l16;
#pragma unroll
    for (int i = 0; i < 4; ++i) {
      const int srow = s0 + wr + i * 16 + quad * 4;
#pragma unroll
      for (int r = 0; r < 4; ++r)
        ob[(size_t)(srow + r) * CC + cloc] = acc[i][j][r];
    }
  }
}

extern "C" void kernel_launch(void* const* d_in, const int* in_sizes, int n_in,
                              void* d_out, int out_size, void* d_ws, size_t ws_size,
                              hipStream_t stream) {
  const float* x  = (const float*)d_in[0];  // [B,S,C]
  const int* eidx = (const int*)d_in[1];    // [M,B]
  const float* dw = (const float*)d_in[2];  // [M,N,C,D]
  const float* db = (const float*)d_in[3];  // [M,N,D]
  const float* uw = (const float*)d_in[4];  // [M,N,D,C]
  float* out = (float*)d_out;               // [M,B,S,C]

  char* ws = (char*)d_ws;
  u16* xb  = (u16*)(ws);                                   // 32 MB: [B,S,C] bf16
  u16* wdT = (u16*)(ws + (size_t)32 * 1024 * 1024);        //  8 MB: [M,N,D,C] bf16
  u16* wuT = (u16*)(ws + (size_t)40 * 1024 * 1024);        //  8 MB: [M,N,C,D] bf16
  u16* zb  = (u16*)(ws + (size_t)48 * 1024 * 1024);        // 16 MB: [M,B,S,D] bf16

  const int nx = BB * SS * CC;  // 16M
  cvt_f32_bf16<<<dim3(nx / 4 / 256), dim3(256), 0, stream>>>(x, xb, nx);
  // down_w: (C,D) slabs -> (D,C)
  transpose_cvt<<<dim3(DD / 32, CC / 32, MM * NN), dim3(256), 0, stream>>>(dw, wdT, CC, DD);
  // up_w: (D,C) slabs -> (C,D)
  transpose_cvt<<<dim3(CC / 32, DD / 32, MM * NN), dim3(256), 0, stream>>>(uw, wuT, DD, CC);

  gemm_down<<<dim3(DD / 128, SS / 128, MM * BB), dim3(256), 0, stream>>>(xb, wdT, db, eidx, zb);
  gemm_up<<<dim3(CC / 128, SS / 128, MM * BB), dim3(256), 0, stream>>>(zb, wuT, eidx, out);
}

// Round 2
// 275.598 us; speedup vs baseline: 1.0164x; 1.0164x over previous
//
#include <hip/hip_runtime.h>
#include <stdint.h>

typedef unsigned short u16;
typedef __bf16 bf16x8 __attribute__((ext_vector_type(8)));
typedef float f32x4 __attribute__((ext_vector_type(4)));

#define MM 2
#define NN 8
#define CC 1024
#define DD 256
#define BB 32
#define SS 512

__device__ __forceinline__ u16 f2bf(float f) {
  uint32_t u = __float_as_uint(f);
  u += 0x7FFFu + ((u >> 16) & 1u);   // round-to-nearest-even
  return (u16)(u >> 16);
}

__device__ __forceinline__ void async16(const void* g, void* l) {
  __builtin_amdgcn_global_load_lds(
      (const __attribute__((address_space(1))) uint32_t*)g,
      (__attribute__((address_space(3))) uint32_t*)l, 16, 0, 0);
}

// ---------------- prep: cvt x + transpose both weights, one launch ----------
// blocks [0, 16384)                : x fp32 -> bf16 (1024 elems/block)
// blocks [16384, 16384+4096)       : down_w (C,D) slabs -> (D,C) bf16
// blocks [16384+4096, 16384+8192)  : up_w (D,C) slabs -> (C,D) bf16
#define CVT_BLOCKS 16384
#define T_BLOCKS 4096
__global__ __launch_bounds__(256) void prep(
    const float* __restrict__ x, u16* __restrict__ xb,
    const float* __restrict__ dw, u16* __restrict__ wdT,
    const float* __restrict__ uw, u16* __restrict__ wuT) {
  const int bid = blockIdx.x;
  if (bid < CVT_BLOCKS) {
    int i = (bid * 256 + threadIdx.x) * 4;
    float4 v = *reinterpret_cast<const float4*>(x + i);
    u16 o[4] = {f2bf(v.x), f2bf(v.y), f2bf(v.z), f2bf(v.w)};
    *reinterpret_cast<uint2*>(xb + i) = *reinterpret_cast<const uint2*>(o);
    return;
  }
  __shared__ float tile[32][33];
  const float* src;
  u16* dst;
  int R, L, bx, by, slab;
  if (bid < CVT_BLOCKS + T_BLOCKS) {
    int t = bid - CVT_BLOCKS;
    slab = t >> 8;                 // 16 slabs, 256 tiles each (8 x 32)
    int t2 = t & 255;
    bx = t2 & 7;  by = t2 >> 3;    // L/32=8, R/32=32
    R = CC; L = DD;
    src = dw; dst = wdT;
  } else {
    int t = bid - CVT_BLOCKS - T_BLOCKS;
    slab = t >> 8;                 // 256 tiles each (32 x 8)
    int t2 = t & 255;
    bx = t2 & 31; by = t2 >> 5;    // L/32=32, R/32=8
    R = DD; L = CC;
    src = uw; dst = wuT;
  }
  src += (size_t)slab * R * L;
  dst += (size_t)slab * R * L;
  const int c0 = bx * 32, r0 = by * 32;
  const int tx = threadIdx.x & 31, ty = threadIdx.x >> 5;
#pragma unroll
  for (int i = 0; i < 32; i += 8)
    tile[ty + i][tx] = src[(size_t)(r0 + ty + i) * L + c0 + tx];
  __syncthreads();
#pragma unroll
  for (int i = 0; i < 32; i += 8)
    dst[(size_t)(c0 + ty + i) * R + r0 + tx] = f2bf(tile[tx][ty + i]);
}

// ---------------- fused: u = silu(x@Wd + b) @ Wu, z kept in LDS -------------
// grid (S/64=8, M*B=64), 256 threads (4 waves).
// Phase 1: z[64 x 256] = silu(x[64 x 1024] @ WdT^T + b), acc in regs.
//          Wave w owns d-cols [64w, 64w+64).
// z stored in LDS as 8 k-tiles of [64 rows x 32 k] (m97 staging layout).
// Phase 2: for each of 4 c-tiles of 256 cols: u_tile = z @ WuT^T,
//          A-frags straight from z LDS, B staged per 32-k slice.
__global__ __launch_bounds__(256) void fused_adapter(
    const u16* __restrict__ xb, const u16* __restrict__ wdT,
    const u16* __restrict__ wuT, const float* __restrict__ db,
    const int* __restrict__ eidx, float* __restrict__ out) {
  __shared__ __align__(16) u16 smA[64 * 32];     //  4 KB: x staging
  __shared__ __align__(16) u16 smB[256 * 32];    // 16 KB: weight staging
  __shared__ __align__(16) u16 zl[8 * 64 * 32];  // 32 KB: z (8 k-tiles)

  const int pair = blockIdx.y;
  const int m = pair >> 5;
  const int b = pair & 31;
  const int e = eidx[pair];
  const int s0 = blockIdx.x * 64;

  const int tid = threadIdx.x;
  const int lane = tid & 63;
  const int wave = tid >> 6;
  const int quad = lane >> 4;
  const int l16 = lane & 15;

  const int srow = lane >> 2;        // staging row within 16-row group
  const int kc = (lane & 3) * 8;     // staging 16B chunk within 64B row

  // ---- phase 1 global bases ----
  const u16* Ab = xb + ((size_t)b * SS + s0) * CC;                  // [64 x 1024]
  const u16* Bd = wdT + (size_t)(m * NN + e) * DD * CC;             // [256 x 1024]
  const u16* gA = Ab + (size_t)(wave * 16 + srow) * CC + kc;
  u16* lA = smA + wave * 16 * 32;
  const u16* gB[4];
  u16* lB[4];
#pragma unroll
  for (int t = 0; t < 4; ++t) {
    gB[t] = Bd + (size_t)(t * 64 + wave * 16 + srow) * CC + kc;
    lB[t] = smB + (t * 64 + wave * 16) * 32;
  }

  f32x4 acc[4][4];
#pragma unroll
  for (int i = 0; i < 4; ++i)
#pragma unroll
    for (int j = 0; j < 4; ++j) acc[i][j] = (f32x4){0.f, 0.f, 0.f, 0.f};

  // ---- phase 1: K = 1024 ----
  for (int kk = 0; kk < CC; kk += 32) {
    async16(gA + kk, lA);
#pragma unroll
    for (int t = 0; t < 4; ++t) async16(gB[t] + kk, lB[t]);
    __syncthreads();
    bf16x8 af[4], bfr[4];
#pragma unroll
    for (int i = 0; i < 4; ++i)
      af[i] = *reinterpret_cast<const bf16x8*>(&smA[(i * 16 + l16) * 32 + quad * 8]);
#pragma unroll
    for (int j = 0; j < 4; ++j)
      bfr[j] = *reinterpret_cast<const bf16x8*>(&smB[(wave * 64 + j * 16 + l16) * 32 + quad * 8]);
#pragma unroll
    for (int i = 0; i < 4; ++i)
#pragma unroll
      for (int j = 0; j < 4; ++j)
        acc[i][j] = __builtin_amdgcn_mfma_f32_16x16x32_bf16(af[i], bfr[j], acc[i][j], 0, 0, 0);
    __syncthreads();
  }

  // ---- silu + bias, write z into LDS k-tile layout ----
  const float* bias_p = db + (size_t)(m * NN + e) * DD;
#pragma unroll
  for (int j = 0; j < 4; ++j) {
    const int d = wave * 64 + j * 16 + l16;
    const float bias = bias_p[d];
    const int kt = d >> 5;         // which 32-k tile
    const int kl = d & 31;         // col inside tile
#pragma unroll
    for (int i = 0; i < 4; ++i) {
      const int sr = i * 16 + quad * 4;
#pragma unroll
      for (int r = 0; r < 4; ++r) {
        float v = acc[i][j][r] + bias;
        v = v / (1.f + __expf(-v));
        zl[(kt * 64 + sr + r) * 32 + kl] = f2bf(v);
      }
    }
  }
  __syncthreads();

  // ---- phase 2: u[64 x 1024] = z[64 x 256] @ Wu^T, 4 c-tiles of 256 ----
  const u16* Bu = wuT + (size_t)(m * NN + e) * CC * DD;             // [1024 x 256]
  float* ob = out + ((size_t)pair * SS + s0) * CC;

  for (int ct = 0; ct < 4; ++ct) {
    const u16* gB2[4];
#pragma unroll
    for (int t = 0; t < 4; ++t)
      gB2[t] = Bu + (size_t)(ct * 256 + t * 64 + wave * 16 + srow) * DD + kc;

#pragma unroll
    for (int i = 0; i < 4; ++i)
#pragma unroll
      for (int j = 0; j < 4; ++j) acc[i][j] = (f32x4){0.f, 0.f, 0.f, 0.f};

    for (int kk = 0; kk < DD; kk += 32) {
#pragma unroll
      for (int t = 0; t < 4; ++t) async16(gB2[t] + kk, lB[t]);
      __syncthreads();
      bf16x8 af[4], bfr[4];
      const int it = kk >> 5;
#pragma unroll
      for (int i = 0; i < 4; ++i)
        af[i] = *reinterpret_cast<const bf16x8*>(&zl[(it * 64 + i * 16 + l16) * 32 + quad * 8]);
#pragma unroll
      for (int j = 0; j < 4; ++j)
        bfr[j] = *reinterpret_cast<const bf16x8*>(&smB[(wave * 64 + j * 16 + l16) * 32 + quad * 8]);
#pragma unroll
      for (int i = 0; i < 4; ++i)
#pragma unroll
        for (int j = 0; j < 4; ++j)
          acc[i][j] = __builtin_amdgcn_mfma_f32_16x16x32_bf16(af[i], bfr[j], acc[i][j], 0, 0, 0);
      __syncthreads();
    }

#pragma unroll
    for (int j = 0; j < 4; ++j) {
      const int c = ct * 256 + wave * 64 + j * 16 + l16;
#pragma unroll
      for (int i = 0; i < 4; ++i) {
        const int sr = i * 16 + quad * 4;
#pragma unroll
        for (int r = 0; r < 4; ++r)
          ob[(size_t)(sr + r) * CC + c] = acc[i][j][r];
      }
    }
  }
}

extern "C" void kernel_launch(void* const* d_in, const int* in_sizes, int n_in,
                              void* d_out, int out_size, void* d_ws, size_t ws_size,
                              hipStream_t stream) {
  const float* x  = (const float*)d_in[0];  // [B,S,C]
  const int* eidx = (const int*)d_in[1];    // [M,B]
  const float* dw = (const float*)d_in[2];  // [M,N,C,D]
  const float* db = (const float*)d_in[3];  // [M,N,D]
  const float* uw = (const float*)d_in[4];  // [M,N,D,C]
  float* out = (float*)d_out;               // [M,B,S,C]

  char* ws = (char*)d_ws;
  u16* xb  = (u16*)(ws);                                   // 32 MB: [B,S,C] bf16
  u16* wdT = (u16*)(ws + (size_t)32 * 1024 * 1024);        //  8 MB: [M,N,D,C] bf16
  u16* wuT = (u16*)(ws + (size_t)40 * 1024 * 1024);        //  8 MB: [M,N,C,D] bf16

  prep<<<dim3(CVT_BLOCKS + 2 * T_BLOCKS), dim3(256), 0, stream>>>(
      x, xb, dw, wdT, uw, wuT);
  fused_adapter<<<dim3(SS / 64, MM * BB), dim3(256), 0, stream>>>(
      xb, wdT, wuT, db, eidx, out);
}